// Round 8
// baseline (666.761 us; speedup 1.0000x reference)
//
#include <hip/hip_runtime.h>

#define N_SAMP 8192
#define D_DIM 6144
#define K_CLS 10
#define RCH 128                        // row chunks
#define ROWS_PER_CH (N_SAMP / RCH)     // 64 rows per chunk
#define CGS 2                          // col groups for stream kernel
#define COLS_PER_CG (D_DIM / CGS)      // 3072 cols
#define TPB_S (COLS_PER_CG / 4)        // 768 threads = 12 waves
#define FIN_CG 24                      // finish col groups (256 cols, 1 wave)
#define FIN_COLS (D_DIM / FIN_CG)

typedef float f4 __attribute__((ext_vector_type(4)));

// Device-scope relaxed atomic (coherence-point RMW, no cache dirtying; r1
// lesson: never use threadfence/agent fences per-block).
__device__ __forceinline__ void atom_add_dev(float* p, float v) {
    __hip_atomic_fetch_add(p, v, __ATOMIC_RELAXED, __HIP_MEMORY_SCOPE_AGENT);
}
__device__ __forceinline__ float wave_sum(float x) {
#pragma unroll
    for (int o = 32; o > 0; o >>= 1) x += __shfl_down(x, o, 64);
    return x;
}
__device__ __forceinline__ int wave_sum_i(int x) {
#pragma unroll
    for (int o = 32; o > 0; o >>= 1) x += __shfl_down(x, o, 64);
    return x;
}

// Kernel A: tiny histogram + init. No sort, no scatter, no S1 zero-init
// (partials are written unconditionally by plain stores).
__global__ __launch_bounds__(1024) void histo_init(const int* __restrict__ y,
                                                   int* __restrict__ counts,
                                                   float* __restrict__ s2sum,
                                                   float* __restrict__ out) {
    __shared__ int hred[16][K_CLS];
    const int tid = threadIdx.x;
    const int lane = tid & 63;
    const int wid = tid >> 6;

    const int4 ya = ((const int4*)y)[tid * 2];
    const int4 yb = ((const int4*)y)[tid * 2 + 1];
    const int yy[8] = {ya.x, ya.y, ya.z, ya.w, yb.x, yb.y, yb.z, yb.w};
    int h[K_CLS];
#pragma unroll
    for (int k = 0; k < K_CLS; ++k) h[k] = 0;
#pragma unroll
    for (int i = 0; i < 8; ++i)
#pragma unroll
        for (int k = 0; k < K_CLS; ++k) h[k] += (yy[i] == k) ? 1 : 0;
#pragma unroll
    for (int k = 0; k < K_CLS; ++k) {
        const int s = wave_sum_i(h[k]);
        if (lane == 0) hred[wid][k] = s;
    }
    __syncthreads();
    if (tid < K_CLS) {
        int s = 0;
#pragma unroll
        for (int w = 0; w < 16; ++w) s += hred[w][tid];
        counts[tid] = s;
        s2sum[tid] = 0.f;
    }
    if (tid == K_CLS) *out = 0.f;
}

// Kernel B: pure sequential streaming over X in NATURAL row order.
// One block = 64-row chunk x 3072-col slice (768 thr, 12 waves; grid 2x128 =
// 256 blocks = exactly 1/CU). Per row: wave-uniform class yk; masked FMA into
// 10 statically-indexed register accumulators (rule #20 safe: inner k-loop
// fully unrolled). ~54 VALU per f4 ~= 9us/CU << 33us HBM floor. Addresses are
// affine (the m13 6.3TB/s pattern) -- no LDS, no barriers, no pins, no
// gather: nothing for the scheduler to defeat (r3-r7 lesson: gather loops
// with ds_read->readfirstlane->load chains stalled at 1-2.2 TB/s).
// Partials: plain coalesced stores (NO atomics on the S1 path at all).
__global__ __launch_bounds__(TPB_S, 3) void wcss_stream(
        const float* __restrict__ X, const int* __restrict__ y,
        float* __restrict__ part, float* __restrict__ s2sum) {
    const int tid = threadIdx.x;
    const int lane = tid & 63;
    const int cg = blockIdx.x;              // 0..CGS-1
    const int rc = blockIdx.y;              // 0..RCH-1
    const int col0 = cg * COLS_PER_CG + tid * 4;
    const int rbase = rc * ROWS_PER_CH;

    f4 acc[K_CLS];
    float s2[K_CLS];
#pragma unroll
    for (int k = 0; k < K_CLS; ++k) { acc[k] = (f4){0.f,0.f,0.f,0.f}; s2[k] = 0.f; }

    const float* xp = X + (size_t)rbase * D_DIM + col0;
    const int* yp = y + rbase;

#pragma unroll 8
    for (int r = 0; r < ROWS_PER_CH; ++r) {
        const int yk = __builtin_amdgcn_readfirstlane(yp[r]);   // wave-uniform
        const f4 v = *(const f4*)(xp + (size_t)r * D_DIM);      // affine addr
        const float dot = v.x*v.x + v.y*v.y + v.z*v.z + v.w*v.w;
#pragma unroll
        for (int k = 0; k < K_CLS; ++k) {                        // static idx
            const float m = (yk == k) ? 1.0f : 0.0f;             // SGPR mask
            acc[k] += v * m;
            s2[k] = fmaf(m, dot, s2[k]);
        }
    }

    // per-chunk partial sums: plain coalesced 16B stores (40KB/block)
#pragma unroll
    for (int k = 0; k < K_CLS; ++k)
        *(f4*)(part + ((size_t)(rc * K_CLS + k)) * D_DIM + col0) = acc[k];

    // s2: wave-reduce then one device-scope atomic per class per wave
#pragma unroll
    for (int k = 0; k < K_CLS; ++k) {
        const float rs = wave_sum(s2[k]);
        if (lane == 0) atom_add_dev(&s2sum[k], rs);
    }
}

// Kernel C: finish. 240 blocks (k x 24 col-groups) x 1 wave. Reduce partials
// over 128 chunks (each load: 64 lanes x 16B = contiguous 1KB, coalesced),
// then out += s2_k/(c D K) - sum_col S_col^2/(c^2 D K).
__global__ __launch_bounds__(64) void wcss_finish(const float* __restrict__ part,
                                                  const float* __restrict__ s2sum,
                                                  const int* __restrict__ counts,
                                                  float* __restrict__ out) {
    const int tid = threadIdx.x;            // 0..63
    const int k = blockIdx.x / FIN_CG;
    const int g = blockIdx.x % FIN_CG;
    const int col0 = g * FIN_COLS + tid * 4;
    const float cnt = (float)counts[k];
    const float invDK = 1.0f / ((float)D_DIM * (float)K_CLS);

    f4 S0 = {0.f,0.f,0.f,0.f}, S1v = {0.f,0.f,0.f,0.f};   // 2-way ILP
#pragma unroll 4
    for (int rc = 0; rc < RCH; rc += 2) {
        S0 += *(const f4*)(part + ((size_t)((rc    ) * K_CLS + k)) * D_DIM + col0);
        S1v += *(const f4*)(part + ((size_t)((rc + 1) * K_CLS + k)) * D_DIM + col0);
    }
    const f4 S = S0 + S1v;
    float t = -(S.x*S.x + S.y*S.y + S.z*S.z + S.w*S.w) * invDK / (cnt * cnt);
    if (g == 0 && tid == 0) t += s2sum[k] * invDK / cnt;
    const float r = wave_sum(t);
    if (tid == 0) atomicAdd(out, r);
}

extern "C" void kernel_launch(void* const* d_in, const int* in_sizes, int n_in,
                              void* d_out, int out_size, void* d_ws, size_t ws_size,
                              hipStream_t stream) {
    const float* X = (const float*)d_in[0];
    const int* y = (const int*)d_in[1];

    float* part = (float*)d_ws;                          // RCH*K*D = 31.5 MB
    float* s2sum = part + (size_t)RCH * K_CLS * D_DIM;   // 10 f
    int* counts = (int*)(s2sum + K_CLS);                 // 10 i
    float* out = (float*)d_out;

    histo_init<<<dim3(1), dim3(1024), 0, stream>>>(y, counts, s2sum, out);
    wcss_stream<<<dim3(CGS, RCH), dim3(TPB_S), 0, stream>>>(X, y, part, s2sum);
    wcss_finish<<<dim3(K_CLS * FIN_CG), dim3(64), 0, stream>>>(part, s2sum,
                                                               counts, out);
}